// Round 3
// baseline (228.772 us; speedup 1.0000x reference)
//
#include <hip/hip_runtime.h>

// ---------------------------------------------------------------------------
// DistanceLoss pipeline on MI355X (gfx950)  — R17
//
// R4: tuple-gather factored out of embed GEMM (Y = X@Wsplit^T, 16.8 GFLOP).
// R9: split-K=2 GEMMs (pipelined global_load_lds ring), 512/648 blocks.
// R10: build_e2 sample-tiled (Y read once, 40 KB LDS).
// R15: gemm_ring 512 threads (8 waves): -3.3us.
// R16: pair-schedule (neutral: it shortened prefetch distance to <1 iter);
//      maskT contrast (neutral: D fits L2 -> tail is latency-bound).
// R17a: gemm_ring tile-granular 4-stage ring, DISTANCE-3 prefetch with
//       counted vmcnt(4)/(2)/(0) — loads stay in flight across 2 barriers.
// R17b: tail fusion: record_finish+contrast_rows+final -> tail_fused
//       (75 blocks, one per query; masks recomputed per-block from record,
//       integer-exact -> bitwise-identical thr/mask/msum).
//
//  1. prep: W fp32->split bf16; X bf16; zero record/sq
//  2. gemm_ring grid(8,32,2):  Yz = X @ Wsplit^T (half-K partials, fp32)
//  3. build_e2: E rows (bf16) from Y0+Y1, sample-tiled; sq via atomics
//  4. gemm_ring grid(36,9,2):  Pz = E @ Esup^T (half-K partials)
//  5. dist_stats: D = sqrt(...), + per-(c,i) stats for query rows
//  6. record_part(675)
//  7. tail_fused(75): thr/mask/msum + masked row sums + logits
// ---------------------------------------------------------------------------

typedef __bf16 bf16x8 __attribute__((ext_vector_type(8)));
typedef float f32x4 __attribute__((ext_vector_type(4)));

#define NQT   3375      // 75*45 query-tuple rows
#define MROWS 4500      // 3375 query rows + 1125 support rows
#define MPAD  4608      // 36 * 128
#define LDD   1152      // padded 1125 -> 9*128
#define BK    32        // K-tile; LDS stride = 32 (UNPADDED: required by global_load_lds)

__constant__ int P0[45] = {0,0,0,0,0,0,0,0,0,
                           1,1,1,1,1,1,1,1,
                           2,2,2,2,2,2,2,
                           3,3,3,3,3,3,
                           4,4,4,4,4,
                           5,5,5,5,
                           6,6,6,
                           7,7,
                           8};
__constant__ int P1[45] = {1,2,3,4,5,6,7,8,9,
                           2,3,4,5,6,7,8,9,
                           3,4,5,6,7,8,9,
                           4,5,6,7,8,9,
                           5,6,7,8,9,
                           6,7,8,9,
                           7,8,9,
                           8,9,
                           9};

__device__ inline unsigned short f2b(float x) {
  __bf16 b = (__bf16)x;               // RNE
  return __builtin_bit_cast(unsigned short, b);
}
__device__ inline float b2f(unsigned int u16) {
  return __uint_as_float(u16 << 16);
}

// async global->LDS, 16B per lane; lds dest must be wave-uniform base + lane*16
__device__ __forceinline__ void gl_lds16(const unsigned short* g, unsigned short* l) {
  __builtin_amdgcn_global_load_lds(
      (__attribute__((address_space(1))) void*)(g),
      (__attribute__((address_space(3))) void*)(l),
      16, 0, 0);
}

// ---- 1: prep: conv W (split) + conv X + zero record/sq ---------------------
__global__ void prep(const float* __restrict__ W, const float* __restrict__ Q,
                     const float* __restrict__ Sp,
                     unsigned short* __restrict__ Ws, unsigned short* __restrict__ X,
                     float* __restrict__ record, float* __restrict__ sq) {
  int b = blockIdx.x, tid = threadIdx.x;
  if (b < 8192) {                                    // W -> split bf16
    int i = b * 256 + tid;
    int i4 = i << 2;
    int o  = i4 >> 12;
    int k  = i4 & 4095;
    int hf = k >> 11;
    int kk = k & 2047;
    float4 v = reinterpret_cast<const float4*>(W)[i];
    ushort4 u;
    u.x = f2b(v.x); u.y = f2b(v.y); u.z = f2b(v.z); u.w = f2b(v.w);
    *reinterpret_cast<ushort4*>(Ws + (size_t)(o + hf * 2048) * 2048 + kk) = u;
  } else if (b < 10240) {                            // X = bf16(Q || S), pad 0
    int i = (b - 8192) * 256 + tid;
    ushort4 u = {0, 0, 0, 0};
    if (i < 384000) {                                // 750*2048/4
      float4 v = reinterpret_cast<const float4*>(Q)[i];
      u.x = f2b(v.x); u.y = f2b(v.y); u.z = f2b(v.z); u.w = f2b(v.w);
    } else if (i < 512000) {                         // + 250*2048/4
      float4 v = reinterpret_cast<const float4*>(Sp)[i - 384000];
      u.x = f2b(v.x); u.y = f2b(v.y); u.z = f2b(v.z); u.w = f2b(v.w);
    }
    reinterpret_cast<ushort4*>(X)[i] = u;
  } else {                                           // zero record + sq
    int i = (b - 10240) * 256 + tid;
    if (i < 4500) record[i] = 0.f;
    else if (i < 4500 + 4608) sq[i - 4500] = 0.f;
  }
}

// ---- 2/4: bf16 MFMA GEMM, C = A @ B^T, 128x128 tile, BK=32, split-K --------
// 512 threads / 8 waves (2x4 wave grid, 64x32 output per wave).
// R17a: 4-stage ring, distance-3 prefetch: issue tile k+3 at iter k; wait
// vmcnt(4) at end of iter k (tile k+1 resident, k+2/k+3 stay in flight
// across the barrier). Never drains to 0 in steady state.
__global__ __launch_bounds__(512)
void gemm_ring(const unsigned short* __restrict__ A, const unsigned short* __restrict__ B,
               int lda, int ldb, int Ksplit,
               float* __restrict__ Pout0, float* __restrict__ Pout1, int ldd) {
  __shared__ unsigned short As[4][128 * BK];   // 4 x 8 KB
  __shared__ unsigned short Bs[4][128 * BK];
  const int tid  = threadIdx.x;
  const int wave = tid >> 6, lane = tid & 63;
  const int quad = lane >> 4, l16 = lane & 15;
  const int wm = (wave >> 2) * 64, wn = (wave & 3) * 32;
  const int m0 = blockIdx.x * 128, n0 = blockIdx.y * 128;
  const int kbase = blockIdx.z * Ksplit;

  f32x4 acc[4][2];
#pragma unroll
  for (int i = 0; i < 4; ++i)
#pragma unroll
    for (int j = 0; j < 2; ++j) {
      f32x4 z = {0.f, 0.f, 0.f, 0.f};
      acc[i][j] = z;
    }

  const int r0  = tid >> 2;                          // 0..127
  const int qsw = (tid & 3) ^ ((tid >> 3) & 3);      // swizzled global chunk
  const int kp0 = qsw * 8;
  const int rsw = (quad ^ ((l16 >> 1) & 3)) * 8;     // conflict-free read slot
  const unsigned short* pa = A + (size_t)(m0 + r0) * lda + kbase + kp0;
  const unsigned short* pb = B + (size_t)(n0 + r0) * ldb + kbase + kp0;
  const int NKi = Ksplit / BK;                       // 32

// one full 128-row stage per array: 512 threads x 16B = 8 KB
#define ISSUE(kk, st) do {                                 \
    gl_lds16(pa + (size_t)(kk) * BK, &As[st][wave * 512]); \
    gl_lds16(pb + (size_t)(kk) * BK, &Bs[st][wave * 512]); \
  } while (0)

  ISSUE(0, 0);
  ISSUE(1, 1);
  ISSUE(2, 2);
  asm volatile("s_waitcnt vmcnt(4)" ::: "memory");   // tile 0 resident
  __builtin_amdgcn_s_barrier();

  for (int k = 0; k < NKi; ++k) {
    if (k + 3 < NKi) ISSUE(k + 3, (k + 3) & 3);      // distance-3 prefetch
    const int sc = k & 3;
    bf16x8 af[4], bfr[2];
#pragma unroll
    for (int t = 0; t < 4; ++t)
      af[t] = *reinterpret_cast<const bf16x8*>(&As[sc][(wm + t * 16 + l16) * BK + rsw]);
#pragma unroll
    for (int t = 0; t < 2; ++t)
      bfr[t] = *reinterpret_cast<const bf16x8*>(&Bs[sc][(wn + t * 16 + l16) * BK + rsw]);
#pragma unroll
    for (int i = 0; i < 4; ++i)
#pragma unroll
      for (int j = 0; j < 2; ++j)
        acc[i][j] = __builtin_amdgcn_mfma_f32_16x16x32_bf16(af[i], bfr[j], acc[i][j], 0, 0, 0);
    if (k + 1 < NKi) {
      // wait for tile k+1 only; leave k+2/k+3 in flight across the barrier
      if (k + 3 < NKi)      asm volatile("s_waitcnt vmcnt(4)" ::: "memory");
      else if (k + 2 < NKi) asm volatile("s_waitcnt vmcnt(2)" ::: "memory");
      else                  asm volatile("s_waitcnt vmcnt(0)" ::: "memory");
      __builtin_amdgcn_s_barrier();
    }
  }
#undef ISSUE
  asm volatile("s_waitcnt vmcnt(0)" ::: "memory");   // drain before stores

  float* Pout = blockIdx.z ? Pout1 : Pout0;
  // epilogue: C/D layout col=lane&15, row=quad*4+reg
#pragma unroll
  for (int i = 0; i < 4; ++i)
#pragma unroll
    for (int j = 0; j < 2; ++j) {
      int col = n0 + wn + j * 16 + l16;
      int rbase = m0 + wm + i * 16 + quad * 4;
      f32x4 v = acc[i][j];
#pragma unroll
      for (int r = 0; r < 4; ++r)
        Pout[(size_t)(rbase + r) * ldd + col] = v[r];
    }
}

// ---- 3: build_e2: sample-tiled E construction ------------------------------
__global__ __launch_bounds__(256)
void build_e2(const float* __restrict__ Y0, const float* __restrict__ Y1,
              const float* __restrict__ bias,
              unsigned short* __restrict__ E, float* __restrict__ sq) {
  int b = blockIdx.x, tid = threadIdx.x;
  if (b >= 400) {                       // zero pad rows
    const size_t base = (size_t)4500 * 2048 / 8;   // uint4 index
    const int total = 108 * 2048 / 8;              // 27648
    uint4 z = {0, 0, 0, 0};
    for (int i = (b - 400) * 256 + tid; i < total; i += 512)
      reinterpret_cast<uint4*>(E)[base + i] = z;
    return;
  }
  int n = b >> 2, q = b & 3;
  int c0 = q * 512;
  __shared__ float Lf[10][512];
  __shared__ float Rf[10][512];
  // stage: 10 frames x 512 cols x {left,right}, Y0+Y1 summed
  for (int e = tid; e < 1280; e += 256) {           // 1280 float4 slots per array
    int f  = e >> 7;                                // 128 float4 per frame
    int cc = (e & 127) << 2;
    const float* ya = Y0 + (size_t)(n * 10 + f) * 4096;
    const float* yb = Y1 + (size_t)(n * 10 + f) * 4096;
    float4 l0 = *reinterpret_cast<const float4*>(ya + c0 + cc);
    float4 l1 = *reinterpret_cast<const float4*>(yb + c0 + cc);
    float4 r0 = *reinterpret_cast<const float4*>(ya + 2048 + c0 + cc);
    float4 r1 = *reinterpret_cast<const float4*>(yb + 2048 + c0 + cc);
    float4 L = {l0.x + l1.x, l0.y + l1.y, l0.z + l1.z, l0.w + l1.w};
    float4 R = {r0.x + r1.x, r0.y + r1.y, r0.z + r1.z, r0.w + r1.w};
    *reinterpret_cast<float4*>(&Lf[f][cc]) = L;
    *reinterpret_cast<float4*>(&Rf[f][cc]) = R;
  }
  __syncthreads();
  int wv = tid >> 6, lane = tid & 63;
  int erow0 = (n < 75) ? n * 45 : NQT + (n - 75) * 45;
  for (int t = wv; t < 45; t += 4) {
    int f0 = P0[t], f1 = P1[t];
    int row = erow0 + t;
    float s = 0.f;
#pragma unroll
    for (int k = 0; k < 8; ++k) {
      int c = lane + 64 * k;                        // 0..511
      float x = Lf[f0][c] + Rf[f1][c] + bias[c0 + c];
      x = fmaxf(x, 0.f);
      unsigned short ob = f2b(x);
      E[(size_t)row * 2048 + c0 + c] = ob;
      float xr = b2f(ob);
      s += xr * xr;                                 // norm from rounded value
    }
#pragma unroll
    for (int sh = 32; sh > 0; sh >>= 1) s += __shfl_down(s, sh, 64);
    if (lane == 0) atomicAdd(&sq[row], s);
  }
}

// ---- 5: dist_stats: D from partials + per-class stats (fused) --------------
__global__ __launch_bounds__(320)
void dist_stats(const float* __restrict__ Pa, const float* __restrict__ Pb,
                const float* __restrict__ sq, float* __restrict__ D,
                float* __restrict__ ave, int* __restrict__ pos,
                float* __restrict__ rmax) {
  __shared__ float drow[LDD];
  __shared__ float sm[5][64];
  int row = blockIdx.x, tid = threadIdx.x;
  float sr = sq[row];
  if (tid < 288) {                                   // 288 float4 = 1152 cols
    int c = tid * 4;
    size_t ix = (size_t)row * LDD / 4 + tid;
    float4 a = reinterpret_cast<const float4*>(Pa)[ix];
    float4 bb = reinterpret_cast<const float4*>(Pb)[ix];
    float4 o;
    o.x = sqrtf(fmaxf(sr + sq[NQT + c + 0] - 2.f * (a.x + bb.x), 0.f));
    o.y = sqrtf(fmaxf(sr + sq[NQT + c + 1] - 2.f * (a.y + bb.y), 0.f));
    o.z = sqrtf(fmaxf(sr + sq[NQT + c + 2] - 2.f * (a.z + bb.z), 0.f));
    o.w = sqrtf(fmaxf(sr + sq[NQT + c + 3] - 2.f * (a.w + bb.w), 0.f));
    reinterpret_cast<float4*>(D)[ix] = o;
    *reinterpret_cast<float4*>(&drow[c]) = o;
  }
  __syncthreads();
  if (row >= NQT) return;                            // support rows: D only
  int wv = tid >> 6, lane = tid & 63;                // wv = class 0..4
  const float* p = &drow[wv * 225];
  float best = -1e30f; int bi = 225;
  float gm = -1e30f;
  if (lane < 60) {
#pragma unroll
    for (int r = 0; r < 4; ++r) {
      int j = lane + 60 * r;
      if (j < 225) {
        float v = p[j];
        if (v > best) { best = v; bi = j; }          // first-occurrence (j asc)
        gm = fmaxf(gm, v);
      }
    }
  }
#pragma unroll
  for (int s = 32; s > 0; s >>= 1) {
    float vv = __shfl_down(best, s, 64);
    int   ii = __shfl_down(bi,   s, 64);
    if (vv > best || (vv == best && ii < bi)) { best = vv; bi = ii; }
  }
  sm[wv][lane] = gm;
  __builtin_amdgcn_wave_barrier();
  if (lane < 5) {
    float m = -1e30f;
#pragma unroll
    for (int a = 0; a < 12; ++a) m = fmaxf(m, sm[wv][lane + 5 * a]);
    sm[wv][lane] = m;
  }
  __builtin_amdgcn_wave_barrier();
  if (lane == 0) {
    float s5 = sm[wv][0] + sm[wv][1] + sm[wv][2] + sm[wv][3] + sm[wv][4];
    ave[wv * NQT + row]  = s5 * 0.2f;
    pos[wv * NQT + row]  = bi;
    rmax[wv * NQT + row] = best;
  }
}

// ---- 6a: record counts, 675 blocks (5 classes x 135 chunks of 25) ----------
__global__ void record_part(const float* __restrict__ D, const float* __restrict__ ave,
                            const int* __restrict__ pos, float* __restrict__ record) {
  int b = blockIdx.x;
  int c = b / 135, chunk = b - c * 135;
  int i0 = chunk * 25;
  int tid = threadIdx.x;
  __shared__ int   sp[25];
  __shared__ float sa[25];
  if (tid < 25) {
    sp[tid] = pos[c * NQT + i0 + tid];
    sa[tid] = ave[c * NQT + i0 + tid];
  }
  __syncthreads();
  float cnt[4] = {0.f, 0.f, 0.f, 0.f};
  int gcol[4];
#pragma unroll
  for (int j = 0; j < 4; ++j) {
    int col = tid + j * 256;
    gcol[j] = (col < 900) ? (col < c * 225 ? col : col + 225) : 0;
  }
  const bool act3 = (tid + 768) < 900;
  const float* Dsup = D + (size_t)(NQT + c * 225) * LDD;
  for (int ii = 0; ii < 25; ++ii) {
    const float* row = Dsup + (size_t)sp[ii] * LDD;
    float a = sa[ii];
    cnt[0] += (row[gcol[0]] > a) ? 1.f : 0.f;
    cnt[1] += (row[gcol[1]] > a) ? 1.f : 0.f;
    cnt[2] += (row[gcol[2]] > a) ? 1.f : 0.f;
    if (act3) cnt[3] += (row[gcol[3]] > a) ? 1.f : 0.f;
  }
#pragma unroll
  for (int j = 0; j < 4; ++j) {
    int col = tid + j * 256;
    if (col < 900) atomicAdd(&record[c * 900 + col], cnt[j]);
  }
}

// ---- 7: tail_fused: thr/mask/msum + masked row sums + logits ---------------
// 75 blocks (one per query q). Each block:
//  A) recomputes the 20 (c,mi) thresholds + masks from record into LDS
//     (integer-valued floats: sums exact -> identical thr/mask/msum);
//  B) 45 masked row sums (identical reduction order to old contrast_rows);
//  C) dsum/ssum per class -> out (identical serial order to old final_kernel).
__global__ __launch_bounds__(256)
void tail_fused(const float* __restrict__ D, const float* __restrict__ record,
                const float* __restrict__ rmax, float* __restrict__ out) {
  int q = blockIdx.x;                                // 0..74
  int tid = threadIdx.x;
  int wv = tid >> 6, lane = tid & 63;
  __shared__ float maskT[5 * LDD];                   // 23 KB
  __shared__ float msum_s[5];
  __shared__ float St[5][45];
  for (int i = tid; i < 5 * LDD; i += 256) maskT[i] = 0.f;
  if (tid < 5) msum_s[tid] = 0.f;
  __syncthreads();

  // Phase A: 20 segments (c,mi), one wave each, strided
  for (int seg = wv; seg < 20; seg += 4) {
    int c = seg >> 2, mi = seg & 3;
    const float* rec = record + c * 900 + mi * 225;
    float r0 = (lane < 225) ? rec[lane] : 0.f;
    float r1 = rec[lane + 64];                       // lane+64 < 225 always? 63+64=127 yes
    float r2 = rec[lane + 128];                      // 63+128=191 < 225 ok
    float r3 = (lane + 192 < 225) ? rec[lane + 192] : 0.f;
    float s  = r0 + r1 + r2 + r3;
    float nz = (r0 != 0.f ? 1.f : 0.f) + (r1 != 0.f ? 1.f : 0.f) +
               (r2 != 0.f ? 1.f : 0.f) + (r3 != 0.f ? 1.f : 0.f);
#pragma unroll
    for (int sh = 32; sh > 0; sh >>= 1) {
      s  += __shfl_down(s,  sh, 64);
      nz += __shfl_down(nz, sh, 64);
    }
    s  = __shfl(s,  0, 64);
    nz = __shfl(nz, 0, 64);
    float nzc = nz < 1.f ? 1.f : nz;
    float thr = s / nzc;
    float mcount = 0.f;
    float rv[4] = {r0, r1, r2, r3};
#pragma unroll
    for (int j = 0; j < 4; ++j) {
      int idx = lane + j * 64;
      if (idx < 225) {
        float m = (rv[j] < thr) ? 1.f : 0.f;
        int L = mi * 225 + idx;                      // local col 0..899
        int g = L + (L >= c * 225 ? 225 : 0);        // global support col
        maskT[c * LDD + g] = m;
        mcount += m;
      }
    }
#pragma unroll
    for (int sh = 32; sh > 0; sh >>= 1) mcount += __shfl_down(mcount, sh, 64);
    if (lane == 0) atomicAdd(&msum_s[c], mcount);
  }
  __syncthreads();

  // Phase B: rows t = wv, wv+4, ... (45 rows)
  for (int t = wv; t < 45; t += 4) {
    const float* row = D + (size_t)(q * 45 + t) * LDD;
    float a0 = 0.f, a1 = 0.f, a2 = 0.f, a3 = 0.f, a4 = 0.f;
#pragma unroll
    for (int k = 0; k < 18; ++k) {                   // 18*64 = 1152 cols
      int col = k * 64 + lane;
      float d = row[col];
      a0 += d * maskT[0 * LDD + col];
      a1 += d * maskT[1 * LDD + col];
      a2 += d * maskT[2 * LDD + col];
      a3 += d * maskT[3 * LDD + col];
      a4 += d * maskT[4 * LDD + col];
    }
#pragma unroll
    for (int sh = 32; sh > 0; sh >>= 1) {
      a0 += __shfl_down(a0, sh, 64);
      a1 += __shfl_down(a1, sh, 64);
      a2 += __shfl_down(a2, sh, 64);
      a3 += __shfl_down(a3, sh, 64);
      a4 += __shfl_down(a4, sh, 64);
    }
    if (lane == 0) {
      St[0][t] = a0; St[1][t] = a1; St[2][t] = a2; St[3][t] = a3; St[4][t] = a4;
    }
  }
  __syncthreads();

  // Phase C: per-class aggregate + logits
  if (tid < 5) {
    int c = tid;
    float dsum = 0.f, ssum = 0.f;
    for (int t = 0; t < 45; ++t) {
      dsum += rmax[c * NQT + q * 45 + t];
      ssum += St[c][t];
    }
    float dm = dsum / 45.f;
    float ms = msum_s[c]; if (ms < 1.f) ms = 1.f;
    float contrast = ssum / (ms * 180.f);            // /msum /45 /(WAY-1)
    out[q * 5 + c] = dm;
    out[375 + q * 5 + c] = dm / (contrast + dm);
  }
}

// ---------------------------------------------------------------------------
extern "C" void kernel_launch(void* const* d_in, const int* in_sizes, int n_in,
                              void* d_out, int out_size, void* d_ws, size_t ws_size,
                              hipStream_t stream) {
  const float* support = (const float*)d_in[0];
  // d_in[1] = support_labels (arange//SHOT) -- class gather is a reshape, unused
  const float* queries = (const float*)d_in[2];
  const float* W       = (const float*)d_in[3];
  const float* bias    = (const float*)d_in[4];
  float* out = (float*)d_out;

  // Aliased workspace layout (lifetimes):
  //  [0, 21.2 MB):  Xb (4.2) + Ws (16.8)   -- dead after gemm1 --> reused as Pd1
  //  [21.2, 38.0):  Y0 (fp32 1024x4096)    -- dead after build_e2
  //  [38.0, 59.2):  Dm region: Y1 (dead after build_e2) -> Pd0 -> D
  //  [59.2, 78.1):  Eb (bf16 4608x2048)
  //  then smalls
  char* ws = (char*)d_ws;
  size_t off = 0;
  unsigned short* Xb  = (unsigned short*)(ws + off);
  unsigned short* Wsp = (unsigned short*)(ws + off + 4194304);
  float*          Pd1 = (float*)(ws + off);          off += 21233664;
  float*          Y0  = (float*)(ws + off);          off += (size_t)1024 * 4096 * 4;
  float*          Dm  = (float*)(ws + off);          // Pd0 / final D
  float*          Y1  = (float*)(ws + off);          off += (size_t)MPAD * LDD * 4;
  unsigned short* Eb  = (unsigned short*)(ws + off); off += (size_t)MPAD * 2048 * 2;
  float* sq      = (float*)(ws + off); off += 4608 * 4 + 256;
  float* ave     = (float*)(ws + off); off += 5 * NQT * 4 + 256;
  int*   pos     = (int*)(ws + off);   off += 5 * NQT * 4 + 256;
  float* rmax    = (float*)(ws + off); off += 5 * NQT * 4 + 256;
  float* record  = (float*)(ws + off); off += 5 * 900 * 4 + 256;

  // zero tail: 4500 (record) + 4608 (sq) = 9108 -> 36 blocks
  prep<<<10276, 256, 0, stream>>>(W, queries, support, Wsp, Xb, record, sq);

  dim3 g1(1024 / 128, 4096 / 128, 2);   // 8 x 32 x 2 = 512 blocks, K=1024 each
  gemm_ring<<<g1, 512, 0, stream>>>(Xb, Wsp, 2048, 2048, 1024, Y0, Y1, 4096);

  build_e2<<<402, 256, 0, stream>>>(Y0, Y1, bias, Eb, sq);

  dim3 g2(MPAD / 128, LDD / 128, 2);    // 36 x 9 x 2 = 648 blocks, K=1024 each
  gemm_ring<<<g2, 512, 0, stream>>>(Eb, Eb + (size_t)NQT * 2048, 2048, 2048, 1024,
                                    Dm, Pd1, LDD);

  dist_stats<<<MROWS, 320, 0, stream>>>(Dm, Pd1, sq, Dm, ave, pos, rmax);

  record_part<<<675, 256, 0, stream>>>(Dm, ave, pos, record);
  tail_fused<<<75, 256, 0, stream>>>(Dm, record, rmax, out);
}

// Round 4
// 215.263 us; speedup vs baseline: 1.0628x; 1.0628x over previous
//
#include <hip/hip_runtime.h>

// ---------------------------------------------------------------------------
// DistanceLoss pipeline on MI355X (gfx950)  — R18
//
// R4: tuple-gather factored out of embed GEMM (Y = X@Wsplit^T, 16.8 GFLOP).
// R9: split-K=2 GEMMs (pipelined global_load_lds ring), 512/648 blocks.
// R10: build_e2 sample-tiled; R15: 8-wave gemm (512 thr).
// R16: pair-granule gemm schedule (2 K-tiles / barrier) = best gemm (<=41us).
// R17: tile-granular distance-3 counted vmcnt REGRESSED gemm2 to 48.5us
//      (halved MFMA-per-barrier at 2 blocks/CU); reverted. tail_fused kept.
// R18: R16 gemm + bijective XCD chunk swizzle (648%8==0, 512%8==0):
//      each XCD owns a contiguous tile run -> B/A panel reuse stays in its
//      private L2 (R17 counters: FETCH 42MB vs 18.9MB input = 2.2x overfetch
//      from cross-XCD panel scatter; HBM-miss loads are what the 2-phase
//      pipeline can't hide).
//
//  1. prep: W fp32->split bf16; X bf16; zero record/sq
//  2. gemm_ring grid(8,32,2):  Yz = X @ Wsplit^T (half-K partials, fp32)
//  3. build_e2: E rows (bf16) from Y0+Y1, sample-tiled; sq via atomics
//  4. gemm_ring grid(36,9,2):  Pz = E @ Esup^T (half-K partials)
//  5. dist_stats: D = sqrt(...), + per-(c,i) stats for query rows
//  6. record_part(675)
//  7. tail_fused(75): thr/mask/msum + masked row sums + logits
// ---------------------------------------------------------------------------

typedef __bf16 bf16x8 __attribute__((ext_vector_type(8)));
typedef float f32x4 __attribute__((ext_vector_type(4)));

#define NQT   3375      // 75*45 query-tuple rows
#define MROWS 4500      // 3375 query rows + 1125 support rows
#define MPAD  4608      // 36 * 128
#define LDD   1152      // padded 1125 -> 9*128
#define BK    32        // K-tile; LDS stride = 32 (UNPADDED: required by global_load_lds)

__constant__ int P0[45] = {0,0,0,0,0,0,0,0,0,
                           1,1,1,1,1,1,1,1,
                           2,2,2,2,2,2,2,
                           3,3,3,3,3,3,
                           4,4,4,4,4,
                           5,5,5,5,
                           6,6,6,
                           7,7,
                           8};
__constant__ int P1[45] = {1,2,3,4,5,6,7,8,9,
                           2,3,4,5,6,7,8,9,
                           3,4,5,6,7,8,9,
                           4,5,6,7,8,9,
                           5,6,7,8,9,
                           6,7,8,9,
                           7,8,9,
                           8,9,
                           9};

__device__ inline unsigned short f2b(float x) {
  __bf16 b = (__bf16)x;               // RNE
  return __builtin_bit_cast(unsigned short, b);
}
__device__ inline float b2f(unsigned int u16) {
  return __uint_as_float(u16 << 16);
}

// async global->LDS, 16B per lane; lds dest must be wave-uniform base + lane*16
__device__ __forceinline__ void gl_lds16(const unsigned short* g, unsigned short* l) {
  __builtin_amdgcn_global_load_lds(
      (__attribute__((address_space(1))) void*)(g),
      (__attribute__((address_space(3))) void*)(l),
      16, 0, 0);
}

// ---- 1: prep: conv W (split) + conv X + zero record/sq ---------------------
__global__ void prep(const float* __restrict__ W, const float* __restrict__ Q,
                     const float* __restrict__ Sp,
                     unsigned short* __restrict__ Ws, unsigned short* __restrict__ X,
                     float* __restrict__ record, float* __restrict__ sq) {
  int b = blockIdx.x, tid = threadIdx.x;
  if (b < 8192) {                                    // W -> split bf16
    int i = b * 256 + tid;
    int i4 = i << 2;
    int o  = i4 >> 12;
    int k  = i4 & 4095;
    int hf = k >> 11;
    int kk = k & 2047;
    float4 v = reinterpret_cast<const float4*>(W)[i];
    ushort4 u;
    u.x = f2b(v.x); u.y = f2b(v.y); u.z = f2b(v.z); u.w = f2b(v.w);
    *reinterpret_cast<ushort4*>(Ws + (size_t)(o + hf * 2048) * 2048 + kk) = u;
  } else if (b < 10240) {                            // X = bf16(Q || S), pad 0
    int i = (b - 8192) * 256 + tid;
    ushort4 u = {0, 0, 0, 0};
    if (i < 384000) {                                // 750*2048/4
      float4 v = reinterpret_cast<const float4*>(Q)[i];
      u.x = f2b(v.x); u.y = f2b(v.y); u.z = f2b(v.z); u.w = f2b(v.w);
    } else if (i < 512000) {                         // + 250*2048/4
      float4 v = reinterpret_cast<const float4*>(Sp)[i - 384000];
      u.x = f2b(v.x); u.y = f2b(v.y); u.z = f2b(v.z); u.w = f2b(v.w);
    }
    reinterpret_cast<ushort4*>(X)[i] = u;
  } else {                                           // zero record + sq
    int i = (b - 10240) * 256 + tid;
    if (i < 4500) record[i] = 0.f;
    else if (i < 4500 + 4608) sq[i - 4500] = 0.f;
  }
}

// ---- 2/4: bf16 MFMA GEMM, C = A @ B^T, 128x128 tile, BK=32, split-K --------
// 512 threads / 8 waves (2x4 wave grid, 64x32 output per wave).
// R16 pair schedule: 4-stage ring, TWO K-tiles (16 MFMA + 12 ds_read) per
// vmcnt(0)+barrier. R18: bijective XCD chunk swizzle on the flattened block
// id (requires nwg % 8 == 0: 512 and 648 both qualify) so each XCD's L2
// keeps its A/B panel working set private.
__global__ __launch_bounds__(512)
void gemm_ring(const unsigned short* __restrict__ A, const unsigned short* __restrict__ B,
               int lda, int ldb, int Ksplit,
               float* __restrict__ Pout0, float* __restrict__ Pout1, int ldd) {
  __shared__ unsigned short As[4][128 * BK];   // 4 x 8 KB
  __shared__ unsigned short Bs[4][128 * BK];
  const int tid  = threadIdx.x;
  const int wave = tid >> 6, lane = tid & 63;
  const int quad = lane >> 4, l16 = lane & 15;
  const int wm = (wave >> 2) * 64, wn = (wave & 3) * 32;

  // XCD chunk swizzle: hw dispatches original linear ids round-robin over
  // 8 XCDs; remap so XCD k executes a CONTIGUOUS tile range [k*cpx,(k+1)*cpx).
  const int gx = gridDim.x, gy = gridDim.y;
  const int nwg = gx * gy * gridDim.z;
  const int lin = blockIdx.x + gx * (blockIdx.y + gy * blockIdx.z);
  const int cpx = nwg >> 3;                          // nwg % 8 == 0
  const int swz = (lin & 7) * cpx + (lin >> 3);
  const int bz  = swz / (gx * gy);
  const int rem = swz - bz * gx * gy;
  const int by  = rem / gx;
  const int bx  = rem - by * gx;

  const int m0 = bx * 128, n0 = by * 128;
  const int kbase = bz * Ksplit;

  f32x4 acc[4][2];
#pragma unroll
  for (int i = 0; i < 4; ++i)
#pragma unroll
    for (int j = 0; j < 2; ++j) {
      f32x4 z = {0.f, 0.f, 0.f, 0.f};
      acc[i][j] = z;
    }

  const int r0  = tid >> 2;                          // 0..127
  const int qsw = (tid & 3) ^ ((tid >> 3) & 3);      // swizzled global chunk
  const int kp0 = qsw * 8;
  const int rsw = (quad ^ ((l16 >> 1) & 3)) * 8;     // conflict-free read slot
  const unsigned short* pa = A + (size_t)(m0 + r0) * lda + kbase + kp0;
  const unsigned short* pb = B + (size_t)(n0 + r0) * ldb + kbase + kp0;
  const int NKi = Ksplit / BK;                       // 32 (even)

// one full 128-row stage per array: 512 threads x 16B = 8 KB
#define ISSUE(kk, st) do {                                 \
    gl_lds16(pa + (size_t)(kk) * BK, &As[st][wave * 512]); \
    gl_lds16(pb + (size_t)(kk) * BK, &Bs[st][wave * 512]); \
  } while (0)

  ISSUE(0, 0);
  ISSUE(1, 1);
  asm volatile("s_waitcnt vmcnt(0)" ::: "memory");   // tiles 0,1 resident
  __builtin_amdgcn_s_barrier();

  for (int kp = 0; kp < NKi; kp += 2) {
    if (kp + 2 < NKi) {                              // prefetch next pair
      ISSUE(kp + 2, (kp + 2) & 3);
      ISSUE(kp + 3, (kp + 3) & 3);
    }
    const int s0 = kp & 3, s1 = s0 | 1;              // kp even: s0 in {0,2}
    bf16x8 a0[4], a1[4], b0[2], b1[2];
#pragma unroll
    for (int t = 0; t < 4; ++t) {
      a0[t] = *reinterpret_cast<const bf16x8*>(&As[s0][(wm + t * 16 + l16) * BK + rsw]);
      a1[t] = *reinterpret_cast<const bf16x8*>(&As[s1][(wm + t * 16 + l16) * BK + rsw]);
    }
#pragma unroll
    for (int t = 0; t < 2; ++t) {
      b0[t] = *reinterpret_cast<const bf16x8*>(&Bs[s0][(wn + t * 16 + l16) * BK + rsw]);
      b1[t] = *reinterpret_cast<const bf16x8*>(&Bs[s1][(wn + t * 16 + l16) * BK + rsw]);
    }
#pragma unroll
    for (int i = 0; i < 4; ++i)
#pragma unroll
      for (int j = 0; j < 2; ++j)
        acc[i][j] = __builtin_amdgcn_mfma_f32_16x16x32_bf16(a0[i], b0[j], acc[i][j], 0, 0, 0);
#pragma unroll
    for (int i = 0; i < 4; ++i)
#pragma unroll
      for (int j = 0; j < 2; ++j)
        acc[i][j] = __builtin_amdgcn_mfma_f32_16x16x32_bf16(a1[i], b1[j], acc[i][j], 0, 0, 0);
    if (kp + 2 < NKi) {
      asm volatile("s_waitcnt vmcnt(0)" ::: "memory"); // own DMA landed
      __builtin_amdgcn_s_barrier();                    // everyone's landed
    }
  }
#undef ISSUE
  asm volatile("s_waitcnt vmcnt(0)" ::: "memory");   // drain before stores

  float* Pout = bz ? Pout1 : Pout0;
  // epilogue: C/D layout col=lane&15, row=quad*4+reg
#pragma unroll
  for (int i = 0; i < 4; ++i)
#pragma unroll
    for (int j = 0; j < 2; ++j) {
      int col = n0 + wn + j * 16 + l16;
      int rbase = m0 + wm + i * 16 + quad * 4;
      f32x4 v = acc[i][j];
#pragma unroll
      for (int r = 0; r < 4; ++r)
        Pout[(size_t)(rbase + r) * ldd + col] = v[r];
    }
}

// ---- 3: build_e2: sample-tiled E construction ------------------------------
__global__ __launch_bounds__(256)
void build_e2(const float* __restrict__ Y0, const float* __restrict__ Y1,
              const float* __restrict__ bias,
              unsigned short* __restrict__ E, float* __restrict__ sq) {
  int b = blockIdx.x, tid = threadIdx.x;
  if (b >= 400) {                       // zero pad rows
    const size_t base = (size_t)4500 * 2048 / 8;   // uint4 index
    const int total = 108 * 2048 / 8;              // 27648
    uint4 z = {0, 0, 0, 0};
    for (int i = (b - 400) * 256 + tid; i < total; i += 512)
      reinterpret_cast<uint4*>(E)[base + i] = z;
    return;
  }
  int n = b >> 2, q = b & 3;
  int c0 = q * 512;
  __shared__ float Lf[10][512];
  __shared__ float Rf[10][512];
  // stage: 10 frames x 512 cols x {left,right}, Y0+Y1 summed
  for (int e = tid; e < 1280; e += 256) {           // 1280 float4 slots per array
    int f  = e >> 7;                                // 128 float4 per frame
    int cc = (e & 127) << 2;
    const float* ya = Y0 + (size_t)(n * 10 + f) * 4096;
    const float* yb = Y1 + (size_t)(n * 10 + f) * 4096;
    float4 l0 = *reinterpret_cast<const float4*>(ya + c0 + cc);
    float4 l1 = *reinterpret_cast<const float4*>(yb + c0 + cc);
    float4 r0 = *reinterpret_cast<const float4*>(ya + 2048 + c0 + cc);
    float4 r1 = *reinterpret_cast<const float4*>(yb + 2048 + c0 + cc);
    float4 L = {l0.x + l1.x, l0.y + l1.y, l0.z + l1.z, l0.w + l1.w};
    float4 R = {r0.x + r1.x, r0.y + r1.y, r0.z + r1.z, r0.w + r1.w};
    *reinterpret_cast<float4*>(&Lf[f][cc]) = L;
    *reinterpret_cast<float4*>(&Rf[f][cc]) = R;
  }
  __syncthreads();
  int wv = tid >> 6, lane = tid & 63;
  int erow0 = (n < 75) ? n * 45 : NQT + (n - 75) * 45;
  for (int t = wv; t < 45; t += 4) {
    int f0 = P0[t], f1 = P1[t];
    int row = erow0 + t;
    float s = 0.f;
#pragma unroll
    for (int k = 0; k < 8; ++k) {
      int c = lane + 64 * k;                        // 0..511
      float x = Lf[f0][c] + Rf[f1][c] + bias[c0 + c];
      x = fmaxf(x, 0.f);
      unsigned short ob = f2b(x);
      E[(size_t)row * 2048 + c0 + c] = ob;
      float xr = b2f(ob);
      s += xr * xr;                                 // norm from rounded value
    }
#pragma unroll
    for (int sh = 32; sh > 0; sh >>= 1) s += __shfl_down(s, sh, 64);
    if (lane == 0) atomicAdd(&sq[row], s);
  }
}

// ---- 5: dist_stats: D from partials + per-class stats (fused) --------------
__global__ __launch_bounds__(320)
void dist_stats(const float* __restrict__ Pa, const float* __restrict__ Pb,
                const float* __restrict__ sq, float* __restrict__ D,
                float* __restrict__ ave, int* __restrict__ pos,
                float* __restrict__ rmax) {
  __shared__ float drow[LDD];
  __shared__ float sm[5][64];
  int row = blockIdx.x, tid = threadIdx.x;
  float sr = sq[row];
  if (tid < 288) {                                   // 288 float4 = 1152 cols
    int c = tid * 4;
    size_t ix = (size_t)row * LDD / 4 + tid;
    float4 a = reinterpret_cast<const float4*>(Pa)[ix];
    float4 bb = reinterpret_cast<const float4*>(Pb)[ix];
    float4 o;
    o.x = sqrtf(fmaxf(sr + sq[NQT + c + 0] - 2.f * (a.x + bb.x), 0.f));
    o.y = sqrtf(fmaxf(sr + sq[NQT + c + 1] - 2.f * (a.y + bb.y), 0.f));
    o.z = sqrtf(fmaxf(sr + sq[NQT + c + 2] - 2.f * (a.z + bb.z), 0.f));
    o.w = sqrtf(fmaxf(sr + sq[NQT + c + 3] - 2.f * (a.w + bb.w), 0.f));
    reinterpret_cast<float4*>(D)[ix] = o;
    *reinterpret_cast<float4*>(&drow[c]) = o;
  }
  __syncthreads();
  if (row >= NQT) return;                            // support rows: D only
  int wv = tid >> 6, lane = tid & 63;                // wv = class 0..4
  const float* p = &drow[wv * 225];
  float best = -1e30f; int bi = 225;
  float gm = -1e30f;
  if (lane < 60) {
#pragma unroll
    for (int r = 0; r < 4; ++r) {
      int j = lane + 60 * r;
      if (j < 225) {
        float v = p[j];
        if (v > best) { best = v; bi = j; }          // first-occurrence (j asc)
        gm = fmaxf(gm, v);
      }
    }
  }
#pragma unroll
  for (int s = 32; s > 0; s >>= 1) {
    float vv = __shfl_down(best, s, 64);
    int   ii = __shfl_down(bi,   s, 64);
    if (vv > best || (vv == best && ii < bi)) { best = vv; bi = ii; }
  }
  sm[wv][lane] = gm;
  __builtin_amdgcn_wave_barrier();
  if (lane < 5) {
    float m = -1e30f;
#pragma unroll
    for (int a = 0; a < 12; ++a) m = fmaxf(m, sm[wv][lane + 5 * a]);
    sm[wv][lane] = m;
  }
  __builtin_amdgcn_wave_barrier();
  if (lane == 0) {
    float s5 = sm[wv][0] + sm[wv][1] + sm[wv][2] + sm[wv][3] + sm[wv][4];
    ave[wv * NQT + row]  = s5 * 0.2f;
    pos[wv * NQT + row]  = bi;
    rmax[wv * NQT + row] = best;
  }
}

// ---- 6a: record counts, 675 blocks (5 classes x 135 chunks of 25) ----------
__global__ void record_part(const float* __restrict__ D, const float* __restrict__ ave,
                            const int* __restrict__ pos, float* __restrict__ record) {
  int b = blockIdx.x;
  int c = b / 135, chunk = b - c * 135;
  int i0 = chunk * 25;
  int tid = threadIdx.x;
  __shared__ int   sp[25];
  __shared__ float sa[25];
  if (tid < 25) {
    sp[tid] = pos[c * NQT + i0 + tid];
    sa[tid] = ave[c * NQT + i0 + tid];
  }
  __syncthreads();
  float cnt[4] = {0.f, 0.f, 0.f, 0.f};
  int gcol[4];
#pragma unroll
  for (int j = 0; j < 4; ++j) {
    int col = tid + j * 256;
    gcol[j] = (col < 900) ? (col < c * 225 ? col : col + 225) : 0;
  }
  const bool act3 = (tid + 768) < 900;
  const float* Dsup = D + (size_t)(NQT + c * 225) * LDD;
  for (int ii = 0; ii < 25; ++ii) {
    const float* row = Dsup + (size_t)sp[ii] * LDD;
    float a = sa[ii];
    cnt[0] += (row[gcol[0]] > a) ? 1.f : 0.f;
    cnt[1] += (row[gcol[1]] > a) ? 1.f : 0.f;
    cnt[2] += (row[gcol[2]] > a) ? 1.f : 0.f;
    if (act3) cnt[3] += (row[gcol[3]] > a) ? 1.f : 0.f;
  }
#pragma unroll
  for (int j = 0; j < 4; ++j) {
    int col = tid + j * 256;
    if (col < 900) atomicAdd(&record[c * 900 + col], cnt[j]);
  }
}

// ---- 7: tail_fused: thr/mask/msum + masked row sums + logits ---------------
// 75 blocks (one per query q). Masks recomputed per-block from record
// (integer-valued floats -> sums exact -> identical thr/mask/msum).
__global__ __launch_bounds__(256)
void tail_fused(const float* __restrict__ D, const float* __restrict__ record,
                const float* __restrict__ rmax, float* __restrict__ out) {
  int q = blockIdx.x;                                // 0..74
  int tid = threadIdx.x;
  int wv = tid >> 6, lane = tid & 63;
  __shared__ float maskT[5 * LDD];                   // 23 KB
  __shared__ float msum_s[5];
  __shared__ float St[5][45];
  for (int i = tid; i < 5 * LDD; i += 256) maskT[i] = 0.f;
  if (tid < 5) msum_s[tid] = 0.f;
  __syncthreads();

  // Phase A: 20 segments (c,mi), one wave each, strided
  for (int seg = wv; seg < 20; seg += 4) {
    int c = seg >> 2, mi = seg & 3;
    const float* rec = record + c * 900 + mi * 225;
    float r0 = rec[lane];
    float r1 = rec[lane + 64];
    float r2 = rec[lane + 128];
    float r3 = (lane + 192 < 225) ? rec[lane + 192] : 0.f;
    float s  = r0 + r1 + r2 + r3;
    float nz = (r0 != 0.f ? 1.f : 0.f) + (r1 != 0.f ? 1.f : 0.f) +
               (r2 != 0.f ? 1.f : 0.f) + (r3 != 0.f ? 1.f : 0.f);
#pragma unroll
    for (int sh = 32; sh > 0; sh >>= 1) {
      s  += __shfl_down(s,  sh, 64);
      nz += __shfl_down(nz, sh, 64);
    }
    s  = __shfl(s,  0, 64);
    nz = __shfl(nz, 0, 64);
    float nzc = nz < 1.f ? 1.f : nz;
    float thr = s / nzc;
    float mcount = 0.f;
    float rv[4] = {r0, r1, r2, r3};
#pragma unroll
    for (int j = 0; j < 4; ++j) {
      int idx = lane + j * 64;
      if (idx < 225) {
        float m = (rv[j] < thr) ? 1.f : 0.f;
        int L = mi * 225 + idx;                      // local col 0..899
        int g = L + (L >= c * 225 ? 225 : 0);        // global support col
        maskT[c * LDD + g] = m;
        mcount += m;
      }
    }
#pragma unroll
    for (int sh = 32; sh > 0; sh >>= 1) mcount += __shfl_down(mcount, sh, 64);
    if (lane == 0) atomicAdd(&msum_s[c], mcount);
  }
  __syncthreads();

  // Phase B: rows t = wv, wv+4, ... (45 rows)
  for (int t = wv; t < 45; t += 4) {
    const float* row = D + (size_t)(q * 45 + t) * LDD;
    float a0 = 0.f, a1 = 0.f, a2 = 0.f, a3 = 0.f, a4 = 0.f;
#pragma unroll
    for (int k = 0; k < 18; ++k) {                   // 18*64 = 1152 cols
      int col = k * 64 + lane;
      float d = row[col];
      a0 += d * maskT[0 * LDD + col];
      a1 += d * maskT[1 * LDD + col];
      a2 += d * maskT[2 * LDD + col];
      a3 += d * maskT[3 * LDD + col];
      a4 += d * maskT[4 * LDD + col];
    }
#pragma unroll
    for (int sh = 32; sh > 0; sh >>= 1) {
      a0 += __shfl_down(a0, sh, 64);
      a1 += __shfl_down(a1, sh, 64);
      a2 += __shfl_down(a2, sh, 64);
      a3 += __shfl_down(a3, sh, 64);
      a4 += __shfl_down(a4, sh, 64);
    }
    if (lane == 0) {
      St[0][t] = a0; St[1][t] = a1; St[2][t] = a2; St[3][t] = a3; St[4][t] = a4;
    }
  }
  __syncthreads();

  // Phase C: per-class aggregate + logits
  if (tid < 5) {
    int c = tid;
    float dsum = 0.f, ssum = 0.f;
    for (int t = 0; t < 45; ++t) {
      dsum += rmax[c * NQT + q * 45 + t];
      ssum += St[c][t];
    }
    float dm = dsum / 45.f;
    float ms = msum_s[c]; if (ms < 1.f) ms = 1.f;
    float contrast = ssum / (ms * 180.f);            // /msum /45 /(WAY-1)
    out[q * 5 + c] = dm;
    out[375 + q * 5 + c] = dm / (contrast + dm);
  }
}

// ---------------------------------------------------------------------------
extern "C" void kernel_launch(void* const* d_in, const int* in_sizes, int n_in,
                              void* d_out, int out_size, void* d_ws, size_t ws_size,
                              hipStream_t stream) {
  const float* support = (const float*)d_in[0];
  // d_in[1] = support_labels (arange//SHOT) -- class gather is a reshape, unused
  const float* queries = (const float*)d_in[2];
  const float* W       = (const float*)d_in[3];
  const float* bias    = (const float*)d_in[4];
  float* out = (float*)d_out;

  // Aliased workspace layout (lifetimes):
  //  [0, 21.2 MB):  Xb (4.2) + Ws (16.8)   -- dead after gemm1 --> reused as Pd1
  //  [21.2, 38.0):  Y0 (fp32 1024x4096)    -- dead after build_e2
  //  [38.0, 59.2):  Dm region: Y1 (dead after build_e2) -> Pd0 -> D
  //  [59.2, 78.1):  Eb (bf16 4608x2048)
  //  then smalls
  char* ws = (char*)d_ws;
  size_t off = 0;
  unsigned short* Xb  = (unsigned short*)(ws + off);
  unsigned short* Wsp = (unsigned short*)(ws + off + 4194304);
  float*          Pd1 = (float*)(ws + off);          off += 21233664;
  float*          Y0  = (float*)(ws + off);          off += (size_t)1024 * 4096 * 4;
  float*          Dm  = (float*)(ws + off);          // Pd0 / final D
  float*          Y1  = (float*)(ws + off);          off += (size_t)MPAD * LDD * 4;
  unsigned short* Eb  = (unsigned short*)(ws + off); off += (size_t)MPAD * 2048 * 2;
  float* sq      = (float*)(ws + off); off += 4608 * 4 + 256;
  float* ave     = (float*)(ws + off); off += 5 * NQT * 4 + 256;
  int*   pos     = (int*)(ws + off);   off += 5 * NQT * 4 + 256;
  float* rmax    = (float*)(ws + off); off += 5 * NQT * 4 + 256;
  float* record  = (float*)(ws + off); off += 5 * 900 * 4 + 256;

  // zero tail: 4500 (record) + 4608 (sq) = 9108 -> 36 blocks
  prep<<<10276, 256, 0, stream>>>(W, queries, support, Wsp, Xb, record, sq);

  dim3 g1(1024 / 128, 4096 / 128, 2);   // 8 x 32 x 2 = 512 blocks, K=1024 each
  gemm_ring<<<g1, 512, 0, stream>>>(Xb, Wsp, 2048, 2048, 1024, Y0, Y1, 4096);

  build_e2<<<402, 256, 0, stream>>>(Y0, Y1, bias, Eb, sq);

  dim3 g2(MPAD / 128, LDD / 128, 2);    // 36 x 9 x 2 = 648 blocks, K=1024 each
  gemm_ring<<<g2, 512, 0, stream>>>(Eb, Eb + (size_t)NQT * 2048, 2048, 2048, 1024,
                                    Dm, Pd1, LDD);

  dist_stats<<<MROWS, 320, 0, stream>>>(Dm, Pd1, sq, Dm, ave, pos, rmax);

  record_part<<<675, 256, 0, stream>>>(Dm, ave, pos, record);
  tail_fused<<<75, 256, 0, stream>>>(Dm, record, rmax, out);
}

// Round 6
// 213.866 us; speedup vs baseline: 1.0697x; 1.0065x over previous
//
#include <hip/hip_runtime.h>

// ---------------------------------------------------------------------------
// DistanceLoss pipeline on MI355X (gfx950)  — R20
//
// R4: tuple-gather factored out of embed GEMM. R9: split-K=2 GEMMs.
// R10: build_e2 sample-tiled. R15: 8-wave gemm. R16: pair schedule (42us).
// R17: distance-3 counted vmcnt regressed (48.5us). tail_fused kept.
// R18: XCD chunk swizzle WORSENED locality (FETCH 42->55MB) - reverted.
// R19: cooperative back_fused FAILED (coop launch under graph capture ->
//      kernel never ran, out=0). Reverted to separate kernels.
// R20: single variable vs R18-minus-swizzle: gemm 3-stage ring (48 KB ->
//      3 blocks/CU; gemm2's 648 blocks fit ONE dispatch generation of 768
//      vs two gens at 64 KB), distance-2 prefetch, counted vmcnt(2) steady
//      state (tile k+1 resident, k+2 in flight across barrier).
//
//  1. prep: W fp32->split bf16; X bf16; zero record/sq
//  2. gemm_ring grid(8,32,2):  Yz = X @ Wsplit^T (half-K partials, fp32)
//  3. build_e2: E rows (bf16) from Y0+Y1, sample-tiled; sq via atomics
//  4. gemm_ring grid(36,9,2):  Pz = E @ Esup^T (half-K partials)
//  5. dist_stats: D = sqrt(...), + per-(c,i) stats for query rows
//  6. record_part(675)
//  7. tail_fused(75): thr/mask/msum + masked row sums + logits
// ---------------------------------------------------------------------------

typedef __bf16 bf16x8 __attribute__((ext_vector_type(8)));
typedef float f32x4 __attribute__((ext_vector_type(4)));

#define NQT   3375      // 75*45 query-tuple rows
#define MROWS 4500      // 3375 query rows + 1125 support rows
#define MPAD  4608      // 36 * 128
#define LDD   1152      // padded 1125 -> 9*128
#define BK    32        // K-tile; LDS stride = 32 (UNPADDED: required by global_load_lds)

__constant__ int P0[45] = {0,0,0,0,0,0,0,0,0,
                           1,1,1,1,1,1,1,1,
                           2,2,2,2,2,2,2,
                           3,3,3,3,3,3,
                           4,4,4,4,4,
                           5,5,5,5,
                           6,6,6,
                           7,7,
                           8};
__constant__ int P1[45] = {1,2,3,4,5,6,7,8,9,
                           2,3,4,5,6,7,8,9,
                           3,4,5,6,7,8,9,
                           4,5,6,7,8,9,
                           5,6,7,8,9,
                           6,7,8,9,
                           7,8,9,
                           8,9,
                           9};

__device__ inline unsigned short f2b(float x) {
  __bf16 b = (__bf16)x;               // RNE
  return __builtin_bit_cast(unsigned short, b);
}
__device__ inline float b2f(unsigned int u16) {
  return __uint_as_float(u16 << 16);
}

// async global->LDS, 16B per lane; lds dest must be wave-uniform base + lane*16
__device__ __forceinline__ void gl_lds16(const unsigned short* g, unsigned short* l) {
  __builtin_amdgcn_global_load_lds(
      (__attribute__((address_space(1))) void*)(g),
      (__attribute__((address_space(3))) void*)(l),
      16, 0, 0);
}

// ---- 1: prep: conv W (split) + conv X + zero record/sq ---------------------
__global__ void prep(const float* __restrict__ W, const float* __restrict__ Q,
                     const float* __restrict__ Sp,
                     unsigned short* __restrict__ Ws, unsigned short* __restrict__ X,
                     float* __restrict__ record, float* __restrict__ sq) {
  int b = blockIdx.x, tid = threadIdx.x;
  if (b < 8192) {                                    // W -> split bf16
    int i = b * 256 + tid;
    int i4 = i << 2;
    int o  = i4 >> 12;
    int k  = i4 & 4095;
    int hf = k >> 11;
    int kk = k & 2047;
    float4 v = reinterpret_cast<const float4*>(W)[i];
    ushort4 u;
    u.x = f2b(v.x); u.y = f2b(v.y); u.z = f2b(v.z); u.w = f2b(v.w);
    *reinterpret_cast<ushort4*>(Ws + (size_t)(o + hf * 2048) * 2048 + kk) = u;
  } else if (b < 10240) {                            // X = bf16(Q || S), pad 0
    int i = (b - 8192) * 256 + tid;
    ushort4 u = {0, 0, 0, 0};
    if (i < 384000) {                                // 750*2048/4
      float4 v = reinterpret_cast<const float4*>(Q)[i];
      u.x = f2b(v.x); u.y = f2b(v.y); u.z = f2b(v.z); u.w = f2b(v.w);
    } else if (i < 512000) {                         // + 250*2048/4
      float4 v = reinterpret_cast<const float4*>(Sp)[i - 384000];
      u.x = f2b(v.x); u.y = f2b(v.y); u.z = f2b(v.z); u.w = f2b(v.w);
    }
    reinterpret_cast<ushort4*>(X)[i] = u;
  } else {                                           // zero record + sq
    int i = (b - 10240) * 256 + tid;
    if (i < 4500) record[i] = 0.f;
    else if (i < 4500 + 4608) sq[i - 4500] = 0.f;
  }
}

// ---- 2/4: bf16 MFMA GEMM, C = A @ B^T, 128x128 tile, BK=32, split-K --------
// 512 threads / 8 waves (2x4 wave grid, 64x32 output per wave).
// R20: 3-stage ring (48 KB -> 3 blocks/CU), per-tile schedule, corrected
// counted waits: prologue vmcnt(2); steady-state end-of-iter vmcnt(2)
// (tile k+1 resident, k+2 stays in flight across the barrier).
__global__ __launch_bounds__(512)
void gemm_ring(const unsigned short* __restrict__ A, const unsigned short* __restrict__ B,
               int lda, int ldb, int Ksplit,
               float* __restrict__ Pout0, float* __restrict__ Pout1, int ldd) {
  __shared__ unsigned short As[3][128 * BK];   // 3 x 8 KB
  __shared__ unsigned short Bs[3][128 * BK];
  const int tid  = threadIdx.x;
  const int wave = tid >> 6, lane = tid & 63;
  const int quad = lane >> 4, l16 = lane & 15;
  const int wm = (wave >> 2) * 64, wn = (wave & 3) * 32;
  const int m0 = blockIdx.x * 128, n0 = blockIdx.y * 128;
  const int kbase = blockIdx.z * Ksplit;

  f32x4 acc[4][2];
#pragma unroll
  for (int i = 0; i < 4; ++i)
#pragma unroll
    for (int j = 0; j < 2; ++j) {
      f32x4 z = {0.f, 0.f, 0.f, 0.f};
      acc[i][j] = z;
    }

  const int r0  = tid >> 2;                          // 0..127
  const int qsw = (tid & 3) ^ ((tid >> 3) & 3);      // swizzled global chunk
  const int kp0 = qsw * 8;
  const int rsw = (quad ^ ((l16 >> 1) & 3)) * 8;     // conflict-free read slot
  const unsigned short* pa = A + (size_t)(m0 + r0) * lda + kbase + kp0;
  const unsigned short* pb = B + (size_t)(n0 + r0) * ldb + kbase + kp0;
  const int NKi = Ksplit / BK;                       // 32

// one full 128-row stage per array: 512 threads x 16B = 8 KB
#define ISSUE(kk, st) do {                                 \
    gl_lds16(pa + (size_t)(kk) * BK, &As[st][wave * 512]); \
    gl_lds16(pb + (size_t)(kk) * BK, &Bs[st][wave * 512]); \
  } while (0)

  ISSUE(0, 0);
  ISSUE(1, 1);
  asm volatile("s_waitcnt vmcnt(2)" ::: "memory");   // tile 0 resident; 1 in flight
  __builtin_amdgcn_s_barrier();

  int sc = 0;
  for (int k = 0; k < NKi; ++k) {
    int sn = sc + 2; if (sn >= 3) sn -= 3;
    if (k + 2 < NKi) ISSUE(k + 2, sn);               // distance-2 prefetch
    bf16x8 af[4], bfr[2];
#pragma unroll
    for (int t = 0; t < 4; ++t)
      af[t] = *reinterpret_cast<const bf16x8*>(&As[sc][(wm + t * 16 + l16) * BK + rsw]);
#pragma unroll
    for (int t = 0; t < 2; ++t)
      bfr[t] = *reinterpret_cast<const bf16x8*>(&Bs[sc][(wn + t * 16 + l16) * BK + rsw]);
#pragma unroll
    for (int i = 0; i < 4; ++i)
#pragma unroll
      for (int j = 0; j < 2; ++j)
        acc[i][j] = __builtin_amdgcn_mfma_f32_16x16x32_bf16(af[i], bfr[j], acc[i][j], 0, 0, 0);
    if (k + 1 < NKi) {
      // guarantee tile k+1 resident; leave k+2 (if issued) in flight
      if (k + 2 < NKi) asm volatile("s_waitcnt vmcnt(2)" ::: "memory");
      else             asm volatile("s_waitcnt vmcnt(0)" ::: "memory");
      __builtin_amdgcn_s_barrier();
    }
    sc = sc + 1; if (sc >= 3) sc = 0;
  }
#undef ISSUE
  asm volatile("s_waitcnt vmcnt(0)" ::: "memory");   // drain before stores

  float* Pout = blockIdx.z ? Pout1 : Pout0;
  // epilogue: C/D layout col=lane&15, row=quad*4+reg
#pragma unroll
  for (int i = 0; i < 4; ++i)
#pragma unroll
    for (int j = 0; j < 2; ++j) {
      int col = n0 + wn + j * 16 + l16;
      int rbase = m0 + wm + i * 16 + quad * 4;
      f32x4 v = acc[i][j];
#pragma unroll
      for (int r = 0; r < 4; ++r)
        Pout[(size_t)(rbase + r) * ldd + col] = v[r];
    }
}

// ---- 3: build_e2: sample-tiled E construction ------------------------------
__global__ __launch_bounds__(256)
void build_e2(const float* __restrict__ Y0, const float* __restrict__ Y1,
              const float* __restrict__ bias,
              unsigned short* __restrict__ E, float* __restrict__ sq) {
  int b = blockIdx.x, tid = threadIdx.x;
  if (b >= 400) {                       // zero pad rows
    const size_t base = (size_t)4500 * 2048 / 8;   // uint4 index
    const int total = 108 * 2048 / 8;              // 27648
    uint4 z = {0, 0, 0, 0};
    for (int i = (b - 400) * 256 + tid; i < total; i += 512)
      reinterpret_cast<uint4*>(E)[base + i] = z;
    return;
  }
  int n = b >> 2, q = b & 3;
  int c0 = q * 512;
  __shared__ float Lf[10][512];
  __shared__ float Rf[10][512];
  // stage: 10 frames x 512 cols x {left,right}, Y0+Y1 summed
  for (int e = tid; e < 1280; e += 256) {           // 1280 float4 slots per array
    int f  = e >> 7;                                // 128 float4 per frame
    int cc = (e & 127) << 2;
    const float* ya = Y0 + (size_t)(n * 10 + f) * 4096;
    const float* yb = Y1 + (size_t)(n * 10 + f) * 4096;
    float4 l0 = *reinterpret_cast<const float4*>(ya + c0 + cc);
    float4 l1 = *reinterpret_cast<const float4*>(yb + c0 + cc);
    float4 r0 = *reinterpret_cast<const float4*>(ya + 2048 + c0 + cc);
    float4 r1 = *reinterpret_cast<const float4*>(yb + 2048 + c0 + cc);
    float4 L = {l0.x + l1.x, l0.y + l1.y, l0.z + l1.z, l0.w + l1.w};
    float4 R = {r0.x + r1.x, r0.y + r1.y, r0.z + r1.z, r0.w + r1.w};
    *reinterpret_cast<float4*>(&Lf[f][cc]) = L;
    *reinterpret_cast<float4*>(&Rf[f][cc]) = R;
  }
  __syncthreads();
  int wv = tid >> 6, lane = tid & 63;
  int erow0 = (n < 75) ? n * 45 : NQT + (n - 75) * 45;
  for (int t = wv; t < 45; t += 4) {
    int f0 = P0[t], f1 = P1[t];
    int row = erow0 + t;
    float s = 0.f;
#pragma unroll
    for (int k = 0; k < 8; ++k) {
      int c = lane + 64 * k;                        // 0..511
      float x = Lf[f0][c] + Rf[f1][c] + bias[c0 + c];
      x = fmaxf(x, 0.f);
      unsigned short ob = f2b(x);
      E[(size_t)row * 2048 + c0 + c] = ob;
      float xr = b2f(ob);
      s += xr * xr;                                 // norm from rounded value
    }
#pragma unroll
    for (int sh = 32; sh > 0; sh >>= 1) s += __shfl_down(s, sh, 64);
    if (lane == 0) atomicAdd(&sq[row], s);
  }
}

// ---- 5: dist_stats: D from partials + per-class stats (fused) --------------
__global__ __launch_bounds__(320)
void dist_stats(const float* __restrict__ Pa, const float* __restrict__ Pb,
                const float* __restrict__ sq, float* __restrict__ D,
                float* __restrict__ ave, int* __restrict__ pos,
                float* __restrict__ rmax) {
  __shared__ float drow[LDD];
  __shared__ float sm[5][64];
  int row = blockIdx.x, tid = threadIdx.x;
  float sr = sq[row];
  if (tid < 288) {                                   // 288 float4 = 1152 cols
    int c = tid * 4;
    size_t ix = (size_t)row * LDD / 4 + tid;
    float4 a = reinterpret_cast<const float4*>(Pa)[ix];
    float4 bb = reinterpret_cast<const float4*>(Pb)[ix];
    float4 o;
    o.x = sqrtf(fmaxf(sr + sq[NQT + c + 0] - 2.f * (a.x + bb.x), 0.f));
    o.y = sqrtf(fmaxf(sr + sq[NQT + c + 1] - 2.f * (a.y + bb.y), 0.f));
    o.z = sqrtf(fmaxf(sr + sq[NQT + c + 2] - 2.f * (a.z + bb.z), 0.f));
    o.w = sqrtf(fmaxf(sr + sq[NQT + c + 3] - 2.f * (a.w + bb.w), 0.f));
    reinterpret_cast<float4*>(D)[ix] = o;
    *reinterpret_cast<float4*>(&drow[c]) = o;
  }
  __syncthreads();
  if (row >= NQT) return;                            // support rows: D only
  int wv = tid >> 6, lane = tid & 63;                // wv = class 0..4
  const float* p = &drow[wv * 225];
  float best = -1e30f; int bi = 225;
  float gm = -1e30f;
  if (lane < 60) {
#pragma unroll
    for (int r = 0; r < 4; ++r) {
      int j = lane + 60 * r;
      if (j < 225) {
        float v = p[j];
        if (v > best) { best = v; bi = j; }          // first-occurrence (j asc)
        gm = fmaxf(gm, v);
      }
    }
  }
#pragma unroll
  for (int s = 32; s > 0; s >>= 1) {
    float vv = __shfl_down(best, s, 64);
    int   ii = __shfl_down(bi,   s, 64);
    if (vv > best || (vv == best && ii < bi)) { best = vv; bi = ii; }
  }
  sm[wv][lane] = gm;
  __builtin_amdgcn_wave_barrier();
  if (lane < 5) {
    float m = -1e30f;
#pragma unroll
    for (int a = 0; a < 12; ++a) m = fmaxf(m, sm[wv][lane + 5 * a]);
    sm[wv][lane] = m;
  }
  __builtin_amdgcn_wave_barrier();
  if (lane == 0) {
    float s5 = sm[wv][0] + sm[wv][1] + sm[wv][2] + sm[wv][3] + sm[wv][4];
    ave[wv * NQT + row]  = s5 * 0.2f;
    pos[wv * NQT + row]  = bi;
    rmax[wv * NQT + row] = best;
  }
}

// ---- 6a: record counts, 675 blocks (5 classes x 135 chunks of 25) ----------
__global__ void record_part(const float* __restrict__ D, const float* __restrict__ ave,
                            const int* __restrict__ pos, float* __restrict__ record) {
  int b = blockIdx.x;
  int c = b / 135, chunk = b - c * 135;
  int i0 = chunk * 25;
  int tid = threadIdx.x;
  __shared__ int   sp[25];
  __shared__ float sa[25];
  if (tid < 25) {
    sp[tid] = pos[c * NQT + i0 + tid];
    sa[tid] = ave[c * NQT + i0 + tid];
  }
  __syncthreads();
  float cnt[4] = {0.f, 0.f, 0.f, 0.f};
  int gcol[4];
#pragma unroll
  for (int j = 0; j < 4; ++j) {
    int col = tid + j * 256;
    gcol[j] = (col < 900) ? (col < c * 225 ? col : col + 225) : 0;
  }
  const bool act3 = (tid + 768) < 900;
  const float* Dsup = D + (size_t)(NQT + c * 225) * LDD;
  for (int ii = 0; ii < 25; ++ii) {
    const float* row = Dsup + (size_t)sp[ii] * LDD;
    float a = sa[ii];
    cnt[0] += (row[gcol[0]] > a) ? 1.f : 0.f;
    cnt[1] += (row[gcol[1]] > a) ? 1.f : 0.f;
    cnt[2] += (row[gcol[2]] > a) ? 1.f : 0.f;
    if (act3) cnt[3] += (row[gcol[3]] > a) ? 1.f : 0.f;
  }
#pragma unroll
  for (int j = 0; j < 4; ++j) {
    int col = tid + j * 256;
    if (col < 900) atomicAdd(&record[c * 900 + col], cnt[j]);
  }
}

// ---- 7: tail_fused: thr/mask/msum + masked row sums + logits ---------------
// 75 blocks (one per query q). Masks recomputed per-block from record
// (integer-valued floats -> sums exact -> identical thr/mask/msum).
__global__ __launch_bounds__(256)
void tail_fused(const float* __restrict__ D, const float* __restrict__ record,
                const float* __restrict__ rmax, float* __restrict__ out) {
  int q = blockIdx.x;                                // 0..74
  int tid = threadIdx.x;
  int wv = tid >> 6, lane = tid & 63;
  __shared__ float maskT[5 * LDD];                   // 23 KB
  __shared__ float msum_s[5];
  __shared__ float St[5][45];
  for (int i = tid; i < 5 * LDD; i += 256) maskT[i] = 0.f;
  if (tid < 5) msum_s[tid] = 0.f;
  __syncthreads();

  // Phase A: 20 segments (c,mi), one wave each, strided
  for (int seg = wv; seg < 20; seg += 4) {
    int c = seg >> 2, mi = seg & 3;
    const float* rec = record + c * 900 + mi * 225;
    float r0 = rec[lane];
    float r1 = rec[lane + 64];
    float r2 = rec[lane + 128];
    float r3 = (lane + 192 < 225) ? rec[lane + 192] : 0.f;
    float s  = r0 + r1 + r2 + r3;
    float nz = (r0 != 0.f ? 1.f : 0.f) + (r1 != 0.f ? 1.f : 0.f) +
               (r2 != 0.f ? 1.f : 0.f) + (r3 != 0.f ? 1.f : 0.f);
#pragma unroll
    for (int sh = 32; sh > 0; sh >>= 1) {
      s  += __shfl_down(s,  sh, 64);
      nz += __shfl_down(nz, sh, 64);
    }
    s  = __shfl(s,  0, 64);
    nz = __shfl(nz, 0, 64);
    float nzc = nz < 1.f ? 1.f : nz;
    float thr = s / nzc;
    float mcount = 0.f;
    float rv[4] = {r0, r1, r2, r3};
#pragma unroll
    for (int j = 0; j < 4; ++j) {
      int idx = lane + j * 64;
      if (idx < 225) {
        float m = (rv[j] < thr) ? 1.f : 0.f;
        int L = mi * 225 + idx;                      // local col 0..899
        int g = L + (L >= c * 225 ? 225 : 0);        // global support col
        maskT[c * LDD + g] = m;
        mcount += m;
      }
    }
#pragma unroll
    for (int sh = 32; sh > 0; sh >>= 1) mcount += __shfl_down(mcount, sh, 64);
    if (lane == 0) atomicAdd(&msum_s[c], mcount);
  }
  __syncthreads();

  // Phase B: rows t = wv, wv+4, ... (45 rows)
  for (int t = wv; t < 45; t += 4) {
    const float* row = D + (size_t)(q * 45 + t) * LDD;
    float a0 = 0.f, a1 = 0.f, a2 = 0.f, a3 = 0.f, a4 = 0.f;
#pragma unroll
    for (int k = 0; k < 18; ++k) {                   // 18*64 = 1152 cols
      int col = k * 64 + lane;
      float d = row[col];
      a0 += d * maskT[0 * LDD + col];
      a1 += d * maskT[1 * LDD + col];
      a2 += d * maskT[2 * LDD + col];
      a3 += d * maskT[3 * LDD + col];
      a4 += d * maskT[4 * LDD + col];
    }
#pragma unroll
    for (int sh = 32; sh > 0; sh >>= 1) {
      a0 += __shfl_down(a0, sh, 64);
      a1 += __shfl_down(a1, sh, 64);
      a2 += __shfl_down(a2, sh, 64);
      a3 += __shfl_down(a3, sh, 64);
      a4 += __shfl_down(a4, sh, 64);
    }
    if (lane == 0) {
      St[0][t] = a0; St[1][t] = a1; St[2][t] = a2; St[3][t] = a3; St[4][t] = a4;
    }
  }
  __syncthreads();

  // Phase C: per-class aggregate + logits
  if (tid < 5) {
    int c = tid;
    float dsum = 0.f, ssum = 0.f;
    for (int t = 0; t < 45; ++t) {
      dsum += rmax[c * NQT + q * 45 + t];
      ssum += St[c][t];
    }
    float dm = dsum / 45.f;
    float ms = msum_s[c]; if (ms < 1.f) ms = 1.f;
    float contrast = ssum / (ms * 180.f);            // /msum /45 /(WAY-1)
    out[q * 5 + c] = dm;
    out[375 + q * 5 + c] = dm / (contrast + dm);
  }
}

// ---------------------------------------------------------------------------
extern "C" void kernel_launch(void* const* d_in, const int* in_sizes, int n_in,
                              void* d_out, int out_size, void* d_ws, size_t ws_size,
                              hipStream_t stream) {
  const float* support = (const float*)d_in[0];
  // d_in[1] = support_labels (arange//SHOT) -- class gather is a reshape, unused
  const float* queries = (const float*)d_in[2];
  const float* W       = (const float*)d_in[3];
  const float* bias    = (const float*)d_in[4];
  float* out = (float*)d_out;

  // Aliased workspace layout (lifetimes):
  //  [0, 21.2 MB):  Xb (4.2) + Ws (16.8)   -- dead after gemm1 --> reused as Pd1
  //  [21.2, 38.0):  Y0 (fp32 1024x4096)    -- dead after build_e2
  //  [38.0, 59.2):  Dm region: Y1 (dead after build_e2) -> Pd0 -> D
  //  [59.2, 78.1):  Eb (bf16 4608x2048)
  //  then smalls
  char* ws = (char*)d_ws;
  size_t off = 0;
  unsigned short* Xb  = (unsigned short*)(ws + off);
  unsigned short* Wsp = (unsigned short*)(ws + off + 4194304);
  float*          Pd1 = (float*)(ws + off);          off += 21233664;
  float*          Y0  = (float*)(ws + off);          off += (size_t)1024 * 4096 * 4;
  float*          Dm  = (float*)(ws + off);          // Pd0 / final D
  float*          Y1  = (float*)(ws + off);          off += (size_t)MPAD * LDD * 4;
  unsigned short* Eb  = (unsigned short*)(ws + off); off += (size_t)MPAD * 2048 * 2;
  float* sq      = (float*)(ws + off); off += 4608 * 4 + 256;
  float* ave     = (float*)(ws + off); off += 5 * NQT * 4 + 256;
  int*   pos     = (int*)(ws + off);   off += 5 * NQT * 4 + 256;
  float* rmax    = (float*)(ws + off); off += 5 * NQT * 4 + 256;
  float* record  = (float*)(ws + off); off += 5 * 900 * 4 + 256;

  // zero tail: 4500 (record) + 4608 (sq) = 9108 -> 36 blocks
  prep<<<10276, 256, 0, stream>>>(W, queries, support, Wsp, Xb, record, sq);

  dim3 g1(1024 / 128, 4096 / 128, 2);   // 8 x 32 x 2 = 512 blocks, K=1024 each
  gemm_ring<<<g1, 512, 0, stream>>>(Xb, Wsp, 2048, 2048, 1024, Y0, Y1, 4096);

  build_e2<<<402, 256, 0, stream>>>(Y0, Y1, bias, Eb, sq);

  dim3 g2(MPAD / 128, LDD / 128, 2);    // 36 x 9 x 2 = 648 blocks, K=1024 each
  gemm_ring<<<g2, 512, 0, stream>>>(Eb, Eb + (size_t)NQT * 2048, 2048, 2048, 1024,
                                    Dm, Pd1, LDD);

  dist_stats<<<MROWS, 320, 0, stream>>>(Dm, Pd1, sq, Dm, ave, pos, rmax);

  record_part<<<675, 256, 0, stream>>>(Dm, ave, pos, record);
  tail_fused<<<75, 256, 0, stream>>>(Dm, record, rmax, out);
}